// Round 3
// baseline (263.065 us; speedup 1.0000x reference)
//
#include <hip/hip_runtime.h>
#include <math.h>

#define L_LEN 16384
#define M_LEN 8192
#define KT_LEN 4096
#define BB 32
#define NTPL 50
#define SPEC_STRIDE 8224   // complex slots per signal (>= 8193)
#define NSIG 166           // 64 x-signals + 2 w-signals + 100 templates
#define NT 1024            // threads per FFT block (2 blocks/CU -> 32 waves/CU)

__device__ __forceinline__ float2 cmul(float2 a, float2 b) {
    return make_float2(a.x*b.x - a.y*b.y, a.x*b.y + a.y*b.x);
}
__device__ __forceinline__ float2 cmulc(float2 a, float2 b) { // a * conj(b)
    return make_float2(a.x*b.x + a.y*b.y, a.y*b.x - a.x*b.y);
}
// LDS bank-swizzle: bijective, keeps array at exactly 8192 float2 (64 KB).
__device__ __forceinline__ int swz(int i) { return i ^ ((i >> 4) & 15); }

// Position of frequency f after 6 radix-4 DIF stages + 1 radix-2 (digit-reverse).
__device__ __forceinline__ int pos4(int f) {
    return ((f & 3) << 11) | (((f >> 2) & 3) << 9) | (((f >> 4) & 3) << 7) |
           (((f >> 6) & 3) << 5) | (((f >> 8) & 3) << 3) |
           (((f >> 10) & 3) << 1) | ((f >> 12) & 1);
}

// T16[k] = e^{-2*pi*i*k/16384}, k in [0,16384)
__global__ __launch_bounds__(512)
void twiddle_init(float2* __restrict__ T) {
    const int k = blockIdx.x * 512 + threadIdx.x;
    const double a = -M_PI * (double)k / 8192.0;
    T[k] = make_float2((float)cos(a), (float)sin(a));
}

// In-place 8192-pt complex DIF FFT in LDS (swizzled), 6 radix-4 + 1 radix-2.
// SIGN=-1: forward (e^{-i}); SIGN=+1: inverse (e^{+i}).
// Output in digit-reversed order (pos4). The final radix-2 stage is NOT done
// here for SIGN=+1 (the inverse kernel fuses it with the max-reduction).
template<int SIGN, bool DO_FINAL>
__device__ __forceinline__ void fft_stages(float2* A, const float2* __restrict__ T, int tid) {
    #pragma unroll
    for (int s = 0; s < 6; ++s) {
        const int lq = 11 - 2 * s;
        const int q = 1 << lq;
        const int m = 1 << (12 - lq);   // 4096/q
        #pragma unroll 1
        for (int g = tid; g < 2048; g += NT) {
            const int j = g & (q - 1);
            const int base = ((g >> lq) << (lq + 2)) | j;
            float2 x0 = A[swz(base)];
            float2 x1 = A[swz(base + q)];
            float2 x2 = A[swz(base + 2*q)];
            float2 x3 = A[swz(base + 3*q)];
            float2 w1 = T[j * m];
            float2 w2 = T[2 * j * m];
            float2 w3 = T[3 * j * m];
            if (SIGN > 0) { w1.y = -w1.y; w2.y = -w2.y; w3.y = -w3.y; }
            float2 t0 = make_float2(x0.x + x2.x, x0.y + x2.y);
            float2 t2 = make_float2(x0.x - x2.x, x0.y - x2.y);
            float2 t1 = make_float2(x1.x + x3.x, x1.y + x3.y);
            float2 dd = make_float2(x1.x - x3.x, x1.y - x3.y);
            float2 t3 = (SIGN < 0) ? make_float2(dd.y, -dd.x)
                                   : make_float2(-dd.y, dd.x);
            float2 u1 = make_float2(t2.x + t3.x, t2.y + t3.y);
            float2 u2 = make_float2(t0.x - t1.x, t0.y - t1.y);
            float2 u3 = make_float2(t2.x - t3.x, t2.y - t3.y);
            A[swz(base)]       = make_float2(t0.x + t1.x, t0.y + t1.y);
            A[swz(base + q)]   = cmul(u1, w1);
            A[swz(base + 2*q)] = cmul(u2, w2);
            A[swz(base + 3*q)] = cmul(u3, w3);
        }
        __syncthreads();
    }
    if (DO_FINAL) {
        #pragma unroll 1
        for (int g = tid; g < 4096; g += NT) {
            float2 a = A[swz(2*g)], b = A[swz(2*g + 1)];
            A[swz(2*g)]     = make_float2(a.x + b.x, a.y + b.y);
            A[swz(2*g + 1)] = make_float2(a.x - b.x, a.y - b.y);
        }
        __syncthreads();
    }
}

// ---------------------------------------------------------------------------
// Kernel 1: forward real FFTs (length L) via half-length complex FFT.
// One block per signal; natural-order spectrum X[f], f=0..M written to spec.
// ---------------------------------------------------------------------------
__global__ __launch_bounds__(NT, 2)
void fwd_fft_kernel(const float* __restrict__ xi, const float* __restrict__ w,
                    const float* __restrict__ tmpl, const float2* __restrict__ T,
                    float2* __restrict__ spec) {
    __shared__ float2 A[M_LEN];   // 64 KB, swizzled
    const int sig = blockIdx.x;
    const int tid = threadIdx.x;

    const float* src;
    int nre;
    if (sig < 64)      { src = xi   + sig * L_LEN;         nre = L_LEN; }
    else if (sig < 66) { src = w    + (sig - 64) * L_LEN;  nre = L_LEN; }
    else               { src = tmpl + (sig - 66) * KT_LEN; nre = KT_LEN; }
    const int nc = nre >> 1;
    const float2* s2 = (const float2*)src;
    for (int i = tid; i < nc; i += NT)         A[swz(i)] = s2[i];
    for (int i = nc + tid; i < M_LEN; i += NT) A[swz(i)] = make_float2(0.f, 0.f);
    __syncthreads();

    fft_stages<-1, true>(A, T, tid);

    // Untangle packed result to real-signal spectrum X[f], f = 0..M.
    float2* out = spec + (size_t)sig * SPEC_STRIDE;
    for (int f = tid; f <= M_LEN; f += NT) {
        const int fa = f & (M_LEN - 1);
        const int fb = (M_LEN - f) & (M_LEN - 1);
        float2 Za = A[swz(pos4(fa))];
        float2 Zb = A[swz(pos4(fb))];
        float2 E = make_float2(0.5f*(Za.x + Zb.x), 0.5f*(Za.y - Zb.y));
        float2 D = make_float2(Za.x - Zb.x, Za.y + Zb.y);
        float2 O = make_float2(0.5f*D.y, -0.5f*D.x);      // -i/2 * D
        float2 t = T[f];                                  // e^{-i pi f / M}
        float cs = t.x, sn = t.y;
        float2 TO = make_float2(cs*O.x - sn*O.y, cs*O.y + sn*O.x);
        out[f] = make_float2(E.x + TO.x, E.y + TO.y);
    }
}

// ---------------------------------------------------------------------------
// Kernel 1.5: per (b,c) premultiply: D[f] = X[f]*conj(W[f])*e^{-i pi k/M},
// k = (KT-2)*f mod L. In place on spec rows 0..63.
// ---------------------------------------------------------------------------
__global__ __launch_bounds__(512)
void premul_kernel(const float2* __restrict__ T, float2* __restrict__ spec) {
    const int bc = blockIdx.x;            // 0..63
    const int tid = threadIdx.x;
    const int c = bc & 1;
    float2* Xs = spec + (size_t)bc * SPEC_STRIDE;
    const float2* Ws = spec + (size_t)(64 + c) * SPEC_STRIDE;
    for (int f = tid; f <= M_LEN; f += 512) {
        float2 t = cmulc(Xs[f], Ws[f]);
        const int k = (4094 * f) & (L_LEN - 1);
        Xs[f] = cmul(t, T[k]);
    }
}

// ---------------------------------------------------------------------------
// Kernel 2: per (b,n,c): S[f] = D[f]*conj(H[f]); real inverse FFT via
// half-length complex inverse FFT (order irrelevant), then max / hh_sqrt.
// ---------------------------------------------------------------------------
__global__ __launch_bounds__(NT, 2)
void inv_fft_kernel(const float2* __restrict__ spec, const float2* __restrict__ T,
                    const float* __restrict__ hh, float* __restrict__ zarr) {
    __shared__ float2 A[M_LEN];   // 64 KB, swizzled (reused for reduction)
    const int idx = blockIdx.x;
    const int c = idx & 1;
    const int n = (idx >> 1) % NTPL;
    const int b = idx / (2 * NTPL);
    const int tid = threadIdx.x;

    const float2* Ds = spec + (size_t)(b*2 + c)      * SPEC_STRIDE;
    const float2* Hs = spec + (size_t)(66 + n*2 + c) * SPEC_STRIDE;

    // Pass 1: S[f], f=0..M; S[M] kept by tid 0 (8192 % NT == 0).
    float2 SMreg = make_float2(0.f, 0.f);
    for (int f = tid; f <= M_LEN; f += NT) {
        float2 S = cmulc(Ds[f], Hs[f]);
        if (f < M_LEN) A[swz(f)] = S; else SMreg = S;
    }
    __syncthreads();

    // Pass 2: pack Z'[f] = spectrum of the half-length complex IFFT input.
    for (int f = tid; f <= M_LEN/2; f += NT) {
        float2 Sa = A[swz(f)];
        float2 Sb = (f == 0) ? SMreg : A[swz(M_LEN - f)];
        float2 E = make_float2(0.5f*(Sa.x + Sb.x), 0.5f*(Sa.y - Sb.y));
        float2 D = make_float2(Sa.x - Sb.x, Sa.y + Sb.y);
        float2 t = T[f];                  // e^{-i pi f/M}; need e^{+i pi f/M}
        float cs = t.x, sn = -t.y;
        float2 O = make_float2(0.5f*(cs*D.x - sn*D.y), 0.5f*(cs*D.y + sn*D.x));
        float2 Zf = make_float2(E.x - O.y, E.y + O.x);
        A[swz(f)] = Zf;
        if (f > 0 && f < M_LEN/2)
            A[swz(M_LEN - f)] = make_float2(E.x + O.y, O.x - E.y);
    }
    __syncthreads();

    // Inverse FFT stages (final radix-2 fused with max below).
    fft_stages<+1, false>(A, T, tid);

    // Final radix-2 + max over all time samples (re and im of every entry).
    float m = -INFINITY;
    #pragma unroll 1
    for (int g = tid; g < 4096; g += NT) {
        float2 a = A[swz(2*g)], b = A[swz(2*g + 1)];
        m = fmaxf(m, fmaxf(fmaxf(a.x + b.x, a.y + b.y),
                           fmaxf(a.x - b.x, a.y - b.y)));
    }
    __syncthreads();   // all reads of A done before reusing it as scratch
    for (int off = 32; off > 0; off >>= 1)
        m = fmaxf(m, __shfl_xor(m, off));
    const int lane = tid & 63, wv = tid >> 6;   // 16 waves
    float* redf = (float*)A;
    if (lane == 0) redf[wv] = m;
    __syncthreads();
    if (tid == 0) {
        float mm = redf[0];
        for (int i = 1; i < NT/64; ++i) mm = fmaxf(mm, redf[i]);
        zarr[(b*2 + c)*NTPL + n] = mm / ((float)M_LEN * hh[n*2 + c]);
    }
}

// ---------------------------------------------------------------------------
// Kernel 3: tiny CNN/MLP head. One block per batch element.
// ---------------------------------------------------------------------------
__global__ __launch_bounds__(256)
void head_kernel(const float* __restrict__ zarr,
                 const float* __restrict__ W1, const float* __restrict__ b1,
                 const float* __restrict__ W2, const float* __restrict__ b2,
                 const float* __restrict__ W3, const float* __restrict__ b3,
                 const float* __restrict__ W4, const float* __restrict__ b4,
                 float* __restrict__ out) {
    __shared__ float zl[2][NTPL];
    __shared__ float s1[16][48];
    __shared__ float p1[16][16];
    __shared__ float s2[32][14];
    __shared__ float hflat[128];
    __shared__ float h1[32];
    const int b = blockIdx.x, tid = threadIdx.x;

    for (int i = tid; i < 2*NTPL; i += 256) zl[i/NTPL][i%NTPL] = zarr[b*2*NTPL + i];
    __syncthreads();
    for (int i = tid; i < 16*48; i += 256) {
        const int o = i / 48, t = i % 48;
        float acc = b1[o];
        #pragma unroll
        for (int cc = 0; cc < 2; ++cc)
            #pragma unroll
            for (int k = 0; k < 3; ++k)
                acc += zl[cc][t+k] * W1[o*6 + cc*3 + k];
        s1[o][t] = 1.f / (1.f + __expf(-acc));
    }
    __syncthreads();
    for (int i = tid; i < 16*16; i += 256) {
        const int o = i / 16, u = i % 16;
        p1[o][u] = fmaxf(fmaxf(s1[o][3*u], s1[o][3*u+1]), s1[o][3*u+2]);
    }
    __syncthreads();
    for (int i = tid; i < 32*14; i += 256) {
        const int o = i / 14, t = i % 14;
        float acc = b2[o];
        for (int cc = 0; cc < 16; ++cc)
            #pragma unroll
            for (int k = 0; k < 3; ++k)
                acc += p1[cc][t+k] * W2[o*48 + cc*3 + k];
        s2[o][t] = 1.f / (1.f + __expf(-acc));
    }
    __syncthreads();
    for (int i = tid; i < 128; i += 256) {
        const int o = i / 4, u = i % 4;
        hflat[i] = fmaxf(fmaxf(s2[o][3*u], s2[o][3*u+1]), s2[o][3*u+2]);
    }
    __syncthreads();
    if (tid < 32) {
        float acc = b3[tid];
        for (int j = 0; j < 128; ++j) acc += hflat[j] * W3[tid*128 + j];
        h1[tid] = fmaxf(acc, 0.f);
    }
    __syncthreads();
    if (tid < 2) {
        float acc = b4[tid];
        for (int j = 0; j < 32; ++j) acc += h1[j] * W4[tid*32 + j];
        out[b*2 + tid] = acc;
    }
}

extern "C" void kernel_launch(void* const* d_in, const int* in_sizes, int n_in,
                              void* d_out, int out_size, void* d_ws, size_t ws_size,
                              hipStream_t stream) {
    const float* xi   = (const float*)d_in[0];
    const float* Sw   = (const float*)d_in[1];
    const float* tmpl = (const float*)d_in[2];
    const float* hh   = (const float*)d_in[3];
    const float* W1   = (const float*)d_in[4];
    const float* b1   = (const float*)d_in[5];
    const float* W2   = (const float*)d_in[6];
    const float* b2   = (const float*)d_in[7];
    const float* W3   = (const float*)d_in[8];
    const float* b3   = (const float*)d_in[9];
    const float* W4   = (const float*)d_in[10];
    const float* b4   = (const float*)d_in[11];
    float* out = (float*)d_out;

    float2* T16  = (float2*)d_ws;                       // 16384 float2 = 128 KB
    float2* spec = T16 + 16384;                         // NSIG * SPEC_STRIDE float2
    float*  zarr = (float*)(spec + (size_t)NSIG * SPEC_STRIDE);

    twiddle_init<<<dim3(32), dim3(512), 0, stream>>>(T16);
    fwd_fft_kernel<<<dim3(NSIG), dim3(NT), 0, stream>>>(xi, Sw, tmpl, T16, spec);
    premul_kernel<<<dim3(64), dim3(512), 0, stream>>>(T16, spec);
    inv_fft_kernel<<<dim3(BB * NTPL * 2), dim3(NT), 0, stream>>>(spec, T16, hh, zarr);
    head_kernel<<<dim3(BB), dim3(256), 0, stream>>>(zarr, W1, b1, W2, b2, W3, b3, W4, b4, out);
}

// Round 4
// 243.727 us; speedup vs baseline: 1.0793x; 1.0793x over previous
//
#include <hip/hip_runtime.h>
#include <math.h>

#define L_LEN 16384
#define M_LEN 8192
#define KT_LEN 4096
#define BB 32
#define NTPL 50
#define SPEC_STRIDE 8224   // complex slots per signal (>= 8193)
#define NSIG 166           // 64 x-signals + 2 w-signals + 100 templates
#define NT 512

__device__ __forceinline__ float2 cmul(float2 a, float2 b) {
    return make_float2(a.x*b.x - a.y*b.y, a.x*b.y + a.y*b.x);
}
__device__ __forceinline__ float2 cmulc(float2 a, float2 b) { // a * conj(b)
    return make_float2(a.x*b.x + a.y*b.y, a.y*b.x - a.x*b.y);
}
__device__ __forceinline__ float2 addc(float2 a, float2 b) {
    return make_float2(a.x + b.x, a.y + b.y);
}
__device__ __forceinline__ float2 subc(float2 a, float2 b) {
    return make_float2(a.x - b.x, a.y - b.y);
}
__device__ __forceinline__ float2 negc(float2 a) { return make_float2(-a.x, -a.y); }
// SIGN=-1: *(-i) ; SIGN=+1: *(+i)
template<int SIGN>
__device__ __forceinline__ float2 rot90(float2 z) {
    return (SIGN < 0) ? make_float2(z.y, -z.x) : make_float2(-z.y, z.x);
}
template<int SIGN>
__device__ __forceinline__ float2 ldT(const float2* __restrict__ T, int idx) {
    float2 t = T[idx];
    if (SIGN > 0) t.y = -t.y;
    return t;
}

// LDS bank swizzle: conflict-free for strides 512/32/2/1; XOR is even so
// float2-pair adjacency (b128 granules) is preserved. Involution -> bijective.
__device__ __forceinline__ int swz(int i) { return i ^ (((i >> 5) & 15) << 1); }

// Position of frequency f after radix 16,16,16,2 DIF stages (digit reversal).
__device__ __forceinline__ int pos(int f) {
    return ((f & 15) << 9) | (((f >> 4) & 15) << 5) |
           (((f >> 8) & 15) << 1) | ((f >> 12) & 1);
}

// T16[k] = e^{-2*pi*i*k/16384}, k in [0,16384)
__global__ __launch_bounds__(512)
void twiddle_init(float2* __restrict__ T) {
    const int k = blockIdx.x * 512 + threadIdx.x;
    const double a = -M_PI * (double)k / 8192.0;
    T[k] = make_float2((float)cos(a), (float)sin(a));
}

// 16-point DFT in registers, natural in/out order. SIGN=-1 fwd, +1 inv.
template<int SIGN>
__device__ __forceinline__ void dft16(float2 x[16], const float2* __restrict__ T) {
    const float2 w1 = ldT<SIGN>(T, 1024);
    const float2 w2 = ldT<SIGN>(T, 2048);
    const float2 w3 = ldT<SIGN>(T, 3072);
    float2 v[16];
    #pragma unroll
    for (int n1 = 0; n1 < 4; ++n1) {
        float2 a0 = x[n1], a1 = x[n1+4], a2 = x[n1+8], a3 = x[n1+12];
        float2 t0 = addc(a0, a2), t2 = subc(a0, a2);
        float2 t1 = addc(a1, a3), t3 = rot90<SIGN>(subc(a1, a3));
        float2 u0 = addc(t0, t1), u1 = addc(t2, t3);
        float2 u2 = subc(t0, t1), u3 = subc(t2, t3);
        if (n1 == 1) { u1 = cmul(u1, w1); u2 = cmul(u2, w2); u3 = cmul(u3, w3); }
        else if (n1 == 2) { u1 = cmul(u1, w2); u2 = rot90<SIGN>(u2);
                            u3 = rot90<SIGN>(cmul(u3, w2)); }
        else if (n1 == 3) { u1 = cmul(u1, w3); u2 = rot90<SIGN>(cmul(u2, w2));
                            u3 = negc(cmul(u3, w1)); }
        v[0*4+n1] = u0; v[1*4+n1] = u1; v[2*4+n1] = u2; v[3*4+n1] = u3;
    }
    #pragma unroll
    for (int r = 0; r < 4; ++r) {
        float2 a0 = v[r*4+0], a1 = v[r*4+1], a2 = v[r*4+2], a3 = v[r*4+3];
        float2 t0 = addc(a0, a2), t2 = subc(a0, a2);
        float2 t1 = addc(a1, a3), t3 = rot90<SIGN>(subc(a1, a3));
        x[r]    = addc(t0, t1); x[r+4]  = addc(t2, t3);
        x[r+8]  = subc(t0, t1); x[r+12] = subc(t2, t3);
    }
}

// One in-place radix-16 DIF stage: read A[base+stride*n], dft16, apply outer
// twiddle T^(es*k), write back to the same address set.
template<int SIGN>
__device__ __forceinline__ void fft_stage16(float2* A, const float2* __restrict__ T,
                                            int base, int stride, int es) {
    float2 x[16];
    #pragma unroll
    for (int n = 0; n < 16; ++n) x[n] = A[swz(base + stride*n)];
    dft16<SIGN>(x, T);
    A[swz(base)] = x[0];
    #pragma unroll
    for (int k = 1; k < 16; ++k) {
        float2 w = ldT<SIGN>(T, es * k);
        A[swz(base + stride*k)] = cmul(x[k], w);
    }
}

// ---------------------------------------------------------------------------
// Kernel 1: forward real FFT (length 16384) via 8192-pt complex FFT.
// ---------------------------------------------------------------------------
__global__ __launch_bounds__(NT, 4)
void fwd_fft_kernel(const float* __restrict__ xi, const float* __restrict__ w,
                    const float* __restrict__ tmpl, const float2* __restrict__ T,
                    float2* __restrict__ spec) {
    __shared__ float2 A[M_LEN];   // 64 KB, swizzled
    const int sig = blockIdx.x;
    const int tid = threadIdx.x;

    const float* src;
    int nre;
    if (sig < 64)      { src = xi   + sig * L_LEN;         nre = L_LEN; }
    else if (sig < 66) { src = w    + (sig - 64) * L_LEN;  nre = L_LEN; }
    else               { src = tmpl + (sig - 66) * KT_LEN; nre = KT_LEN; }
    const int nc = nre >> 1;
    const float4* s4 = (const float4*)src;
    #pragma unroll
    for (int m = 0; m < 8; ++m) {
        const int u = 2*tid + 1024*m;
        float4 vv = (u < nc) ? s4[tid + 512*m] : make_float4(0.f, 0.f, 0.f, 0.f);
        ((float4*)A)[swz(u) >> 1] = vv;
    }
    __syncthreads();

    fft_stage16<-1>(A, T, tid, 512, 2*tid);
    __syncthreads();
    { const int blk = tid >> 5, j = tid & 31;
      fft_stage16<-1>(A, T, blk*512 + j, 32, 32*j); }
    __syncthreads();
    { const int blk = tid >> 1, j = tid & 1;
      fft_stage16<-1>(A, T, blk*32 + j, 2, 512*j); }
    __syncthreads();
    // Final radix-2 (stride 1, no twiddle), b128 in-place.
    #pragma unroll
    for (int m = 0; m < 8; ++m) {
        const int gi = swz(2*(tid + 512*m)) >> 1;
        float4 pq = ((float4*)A)[gi];
        ((float4*)A)[gi] = make_float4(pq.x + pq.z, pq.y + pq.w,
                                       pq.x - pq.z, pq.y - pq.w);
    }
    __syncthreads();

    // Untangle packed result to real-signal spectrum X[f], f = 0..M.
    float2* out = spec + (size_t)sig * SPEC_STRIDE;
    #pragma unroll
    for (int m = 0; m < 16; ++m) {
        const int f = tid + 512*m;
        const int fb = (M_LEN - f) & (M_LEN - 1);
        float2 Za = A[swz(pos(f))];
        float2 Zb = A[swz(pos(fb))];
        float2 E = make_float2(0.5f*(Za.x + Zb.x), 0.5f*(Za.y - Zb.y));
        float2 D = make_float2(Za.x - Zb.x, Za.y + Zb.y);
        float2 O = make_float2(0.5f*D.y, -0.5f*D.x);
        float2 t = T[f];
        float2 TO = make_float2(t.x*O.x - t.y*O.y, t.x*O.y + t.y*O.x);
        out[f] = make_float2(E.x + TO.x, E.y + TO.y);
    }
    if (tid == 0) {   // f = 8192: fa = fb = 0
        float2 Za = A[swz(0)];
        float2 E = make_float2(Za.x, 0.f);
        float2 O = make_float2(Za.y, 0.f);
        float2 t = T[M_LEN];                  // (-1, 0)
        float2 TO = make_float2(t.x*O.x, t.x*O.y);
        out[M_LEN] = make_float2(E.x + TO.x, E.y + TO.y);
    }
}

// ---------------------------------------------------------------------------
// Kernel 1.5: per (b,c) premultiply: D[f] = X[f]*conj(W[f])*e^{-i pi k/M}.
// ---------------------------------------------------------------------------
__global__ __launch_bounds__(512)
void premul_kernel(const float2* __restrict__ T, float2* __restrict__ spec) {
    const int bc = blockIdx.x;
    const int tid = threadIdx.x;
    const int c = bc & 1;
    float2* Xs = spec + (size_t)bc * SPEC_STRIDE;
    const float2* Ws = spec + (size_t)(64 + c) * SPEC_STRIDE;
    for (int f = tid; f <= M_LEN; f += 512) {
        float2 t = cmulc(Xs[f], Ws[f]);
        const int k = (4094 * f) & (L_LEN - 1);
        Xs[f] = cmul(t, T[k]);
    }
}

// ---------------------------------------------------------------------------
// Kernel 2: per (b,n,c): S[f] = D[f]*conj(H[f]); Hermitian pack fused into
// the product pass; 3 register radix-16 stages; final radix-2 fused with max.
// ---------------------------------------------------------------------------
__global__ __launch_bounds__(NT, 4)
void inv_fft_kernel(const float2* __restrict__ spec, const float2* __restrict__ T,
                    const float* __restrict__ hh, float* __restrict__ zarr) {
    __shared__ float2 A[M_LEN];   // 64 KB, swizzled (reused for reduction)
    const int idx = blockIdx.x;
    const int c = idx & 1;
    const int n = (idx >> 1) % NTPL;
    const int b = idx / (2 * NTPL);
    const int tid = threadIdx.x;

    const float2* Ds = spec + (size_t)(b*2 + c)      * SPEC_STRIDE;
    const float2* Hs = spec + (size_t)(66 + n*2 + c) * SPEC_STRIDE;
    const float4* D4 = (const float4*)Ds;
    const float4* H4 = (const float4*)Hs;
    const float4* T4 = (const float4*)T;

    // Fused product + Hermitian pack: thread t handles f = 2t+1024m+{0,1}
    // (f in [0,4096)) and partners 8192-f. Writes all of Z'[0..8191].
    #pragma unroll
    for (int m = 0; m < 4; ++m) {
        const int u = 2*tid + 1024*m;
        float4 df = D4[tid + 512*m], hf = H4[tid + 512*m];
        float2 Sa0 = cmulc(make_float2(df.x, df.y), make_float2(hf.x, hf.y));
        float2 Sa1 = cmulc(make_float2(df.z, df.w), make_float2(hf.z, hf.w));
        float2 Sb0 = cmulc(Ds[M_LEN - u],     Hs[M_LEN - u]);
        float2 Sb1 = cmulc(Ds[M_LEN - 1 - u], Hs[M_LEN - 1 - u]);
        float4 tw = T4[tid + 512*m];          // T[u], T[u+1]
        // f = u
        float cs0 = tw.x, sn0 = -tw.y;
        float Ex0 = 0.5f*(Sa0.x + Sb0.x), Ey0 = 0.5f*(Sa0.y - Sb0.y);
        float Dx0 = Sa0.x - Sb0.x,        Dy0 = Sa0.y + Sb0.y;
        float Ox0 = 0.5f*(cs0*Dx0 - sn0*Dy0), Oy0 = 0.5f*(cs0*Dy0 + sn0*Dx0);
        // f = u+1
        float cs1 = tw.z, sn1 = -tw.w;
        float Ex1 = 0.5f*(Sa1.x + Sb1.x), Ey1 = 0.5f*(Sa1.y - Sb1.y);
        float Dx1 = Sa1.x - Sb1.x,        Dy1 = Sa1.y + Sb1.y;
        float Ox1 = 0.5f*(cs1*Dx1 - sn1*Dy1), Oy1 = 0.5f*(cs1*Dy1 + sn1*Dx1);
        ((float4*)A)[swz(u) >> 1] = make_float4(Ex0 - Oy0, Ey0 + Ox0,
                                                Ex1 - Oy1, Ey1 + Ox1);
        if (u > 0) A[swz(M_LEN - u)] = make_float2(Ex0 + Oy0, Ox0 - Ey0);
        A[swz(M_LEN - 1 - u)] = make_float2(Ex1 + Oy1, Ox1 - Ey1);
    }
    if (tid == 0) {   // f = 4096 (self-paired)
        float2 S = cmulc(Ds[4096], Hs[4096]);
        A[swz(4096)] = make_float2(S.x, -S.y);
    }
    __syncthreads();

    fft_stage16<+1>(A, T, tid, 512, 2*tid);
    __syncthreads();
    { const int blk = tid >> 5, j = tid & 31;
      fft_stage16<+1>(A, T, blk*512 + j, 32, 32*j); }
    __syncthreads();
    { const int blk = tid >> 1, j = tid & 1;
      fft_stage16<+1>(A, T, blk*32 + j, 2, 512*j); }
    __syncthreads();

    // Final radix-2 fused with max over re/im of every time sample.
    float mx = -INFINITY;
    #pragma unroll
    for (int m = 0; m < 8; ++m) {
        float4 pq = ((const float4*)A)[swz(2*(tid + 512*m)) >> 1];
        mx = fmaxf(mx, fmaxf(fmaxf(pq.x + pq.z, pq.y + pq.w),
                             fmaxf(pq.x - pq.z, pq.y - pq.w)));
    }
    __syncthreads();   // all reads of A done before reusing it as scratch
    for (int off = 32; off > 0; off >>= 1)
        mx = fmaxf(mx, __shfl_xor(mx, off));
    const int lane = tid & 63, wv = tid >> 6;   // 8 waves
    float* redf = (float*)A;
    if (lane == 0) redf[wv] = mx;
    __syncthreads();
    if (tid == 0) {
        float mm = redf[0];
        for (int i = 1; i < NT/64; ++i) mm = fmaxf(mm, redf[i]);
        zarr[(b*2 + c)*NTPL + n] = mm / ((float)M_LEN * hh[n*2 + c]);
    }
}

// ---------------------------------------------------------------------------
// Kernel 3: tiny CNN/MLP head. One block per batch element.
// ---------------------------------------------------------------------------
__global__ __launch_bounds__(256)
void head_kernel(const float* __restrict__ zarr,
                 const float* __restrict__ W1, const float* __restrict__ b1,
                 const float* __restrict__ W2, const float* __restrict__ b2,
                 const float* __restrict__ W3, const float* __restrict__ b3,
                 const float* __restrict__ W4, const float* __restrict__ b4,
                 float* __restrict__ out) {
    __shared__ float zl[2][NTPL];
    __shared__ float s1[16][48];
    __shared__ float p1[16][16];
    __shared__ float s2[32][14];
    __shared__ float hflat[128];
    __shared__ float h1[32];
    const int b = blockIdx.x, tid = threadIdx.x;

    for (int i = tid; i < 2*NTPL; i += 256) zl[i/NTPL][i%NTPL] = zarr[b*2*NTPL + i];
    __syncthreads();
    for (int i = tid; i < 16*48; i += 256) {
        const int o = i / 48, t = i % 48;
        float acc = b1[o];
        #pragma unroll
        for (int cc = 0; cc < 2; ++cc)
            #pragma unroll
            for (int k = 0; k < 3; ++k)
                acc += zl[cc][t+k] * W1[o*6 + cc*3 + k];
        s1[o][t] = 1.f / (1.f + __expf(-acc));
    }
    __syncthreads();
    for (int i = tid; i < 16*16; i += 256) {
        const int o = i / 16, u = i % 16;
        p1[o][u] = fmaxf(fmaxf(s1[o][3*u], s1[o][3*u+1]), s1[o][3*u+2]);
    }
    __syncthreads();
    for (int i = tid; i < 32*14; i += 256) {
        const int o = i / 14, t = i % 14;
        float acc = b2[o];
        for (int cc = 0; cc < 16; ++cc)
            #pragma unroll
            for (int k = 0; k < 3; ++k)
                acc += p1[cc][t+k] * W2[o*48 + cc*3 + k];
        s2[o][t] = 1.f / (1.f + __expf(-acc));
    }
    __syncthreads();
    for (int i = tid; i < 128; i += 256) {
        const int o = i / 4, u = i % 4;
        hflat[i] = fmaxf(fmaxf(s2[o][3*u], s2[o][3*u+1]), s2[o][3*u+2]);
    }
    __syncthreads();
    if (tid < 32) {
        float acc = b3[tid];
        for (int j = 0; j < 128; ++j) acc += hflat[j] * W3[tid*128 + j];
        h1[tid] = fmaxf(acc, 0.f);
    }
    __syncthreads();
    if (tid < 2) {
        float acc = b4[tid];
        for (int j = 0; j < 32; ++j) acc += h1[j] * W4[tid*32 + j];
        out[b*2 + tid] = acc;
    }
}

extern "C" void kernel_launch(void* const* d_in, const int* in_sizes, int n_in,
                              void* d_out, int out_size, void* d_ws, size_t ws_size,
                              hipStream_t stream) {
    const float* xi   = (const float*)d_in[0];
    const float* Sw   = (const float*)d_in[1];
    const float* tmpl = (const float*)d_in[2];
    const float* hh   = (const float*)d_in[3];
    const float* W1   = (const float*)d_in[4];
    const float* b1   = (const float*)d_in[5];
    const float* W2   = (const float*)d_in[6];
    const float* b2   = (const float*)d_in[7];
    const float* W3   = (const float*)d_in[8];
    const float* b3   = (const float*)d_in[9];
    const float* W4   = (const float*)d_in[10];
    const float* b4   = (const float*)d_in[11];
    float* out = (float*)d_out;

    float2* T16  = (float2*)d_ws;                       // 16384 float2 = 128 KB
    float2* spec = T16 + 16384;                         // NSIG * SPEC_STRIDE float2
    float*  zarr = (float*)(spec + (size_t)NSIG * SPEC_STRIDE);

    twiddle_init<<<dim3(32), dim3(512), 0, stream>>>(T16);
    fwd_fft_kernel<<<dim3(NSIG), dim3(NT), 0, stream>>>(xi, Sw, tmpl, T16, spec);
    premul_kernel<<<dim3(64), dim3(512), 0, stream>>>(T16, spec);
    inv_fft_kernel<<<dim3(BB * NTPL * 2), dim3(NT), 0, stream>>>(spec, T16, hh, zarr);
    head_kernel<<<dim3(BB), dim3(256), 0, stream>>>(zarr, W1, b1, W2, b2, W3, b3, W4, b4, out);
}

// Round 5
// 184.065 us; speedup vs baseline: 1.4292x; 1.3241x over previous
//
#include <hip/hip_runtime.h>
#include <math.h>

#define L_LEN 16384
#define M_LEN 8192
#define KT_LEN 4096
#define BB 32
#define NTPL 50
#define SPEC_STRIDE 8224   // complex slots per signal (>= 8193)
#define NSIG 166           // 64 x-signals + 2 w-signals + 100 templates
#define NT 512

__device__ __forceinline__ float2 cmul(float2 a, float2 b) {
    return make_float2(a.x*b.x - a.y*b.y, a.x*b.y + a.y*b.x);
}
__device__ __forceinline__ float2 cmulc(float2 a, float2 b) { // a * conj(b)
    return make_float2(a.x*b.x + a.y*b.y, a.y*b.x - a.x*b.y);
}
__device__ __forceinline__ float2 addc(float2 a, float2 b) {
    return make_float2(a.x + b.x, a.y + b.y);
}
__device__ __forceinline__ float2 subc(float2 a, float2 b) {
    return make_float2(a.x - b.x, a.y - b.y);
}
__device__ __forceinline__ float2 negc(float2 a) { return make_float2(-a.x, -a.y); }
// SIGN=-1: *(-i) ; SIGN=+1: *(+i)
template<int SIGN>
__device__ __forceinline__ float2 rot90(float2 z) {
    return (SIGN < 0) ? make_float2(z.y, -z.x) : make_float2(-z.y, z.x);
}
template<int SIGN>
__device__ __forceinline__ float2 ldT(const float2* __restrict__ T, int idx) {
    float2 t = T[idx];
    if (SIGN > 0) t.y = -t.y;
    return t;
}

// LDS bank swizzle: conflict-free for strides 512/32/2/1; XOR is even so
// float2-pair adjacency (b128 granules) is preserved. Involution -> bijective.
__device__ __forceinline__ int swz(int i) { return i ^ (((i >> 5) & 15) << 1); }

// Position of frequency f after radix 16,16,16,2 DIF stages (digit reversal).
__device__ __forceinline__ int pos(int f) {
    return ((f & 15) << 9) | (((f >> 4) & 15) << 5) |
           (((f >> 8) & 15) << 1) | ((f >> 12) & 1);
}

// T16[k] = e^{-2*pi*i*k/16384}, k in [0,16384)
__global__ __launch_bounds__(512)
void twiddle_init(float2* __restrict__ T) {
    const int k = blockIdx.x * 512 + threadIdx.x;
    const double a = -M_PI * (double)k / 8192.0;
    T[k] = make_float2((float)cos(a), (float)sin(a));
}

// 16-point DFT in registers, natural in/out order. SIGN=-1 fwd, +1 inv.
// Inner twiddles are compile-time constants: e^{∓i pi/8}, e^{∓i pi/4}, e^{∓3i pi/8}.
template<int SIGN>
__device__ __forceinline__ void dft16(float2 x[16]) {
    const float S = (SIGN < 0) ? -1.f : 1.f;
    const float2 w1 = make_float2(0.9238795325112867f, S * 0.3826834323650898f);
    const float2 w2 = make_float2(0.7071067811865476f, S * 0.7071067811865476f);
    const float2 w3 = make_float2(0.3826834323650898f, S * 0.9238795325112867f);
    float2 v[16];
    #pragma unroll
    for (int n1 = 0; n1 < 4; ++n1) {
        float2 a0 = x[n1], a1 = x[n1+4], a2 = x[n1+8], a3 = x[n1+12];
        float2 t0 = addc(a0, a2), t2 = subc(a0, a2);
        float2 t1 = addc(a1, a3), t3 = rot90<SIGN>(subc(a1, a3));
        float2 u0 = addc(t0, t1), u1 = addc(t2, t3);
        float2 u2 = subc(t0, t1), u3 = subc(t2, t3);
        if (n1 == 1) { u1 = cmul(u1, w1); u2 = cmul(u2, w2); u3 = cmul(u3, w3); }
        else if (n1 == 2) { u1 = cmul(u1, w2); u2 = rot90<SIGN>(u2);
                            u3 = rot90<SIGN>(cmul(u3, w2)); }
        else if (n1 == 3) { u1 = cmul(u1, w3); u2 = rot90<SIGN>(cmul(u2, w2));
                            u3 = negc(cmul(u3, w1)); }
        v[0*4+n1] = u0; v[1*4+n1] = u1; v[2*4+n1] = u2; v[3*4+n1] = u3;
    }
    #pragma unroll
    for (int r = 0; r < 4; ++r) {
        float2 a0 = v[r*4+0], a1 = v[r*4+1], a2 = v[r*4+2], a3 = v[r*4+3];
        float2 t0 = addc(a0, a2), t2 = subc(a0, a2);
        float2 t1 = addc(a1, a3), t3 = rot90<SIGN>(subc(a1, a3));
        x[r]    = addc(t0, t1); x[r+4]  = addc(t2, t3);
        x[r+8]  = subc(t0, t1); x[r+12] = subc(t2, t3);
    }
}

// One in-place radix-16 DIF stage. Outer twiddles T^(es*k), k=1..15, are built
// from a SINGLE table load w = T[es] by a power chain (the 15 scattered
// per-lane loads were the R4 latency bottleneck).
template<int SIGN>
__device__ __forceinline__ void fft_stage16(float2* A, const float2* __restrict__ T,
                                            int base, int stride, int es) {
    float2 x[16];
    #pragma unroll
    for (int n = 0; n < 16; ++n) x[n] = A[swz(base + stride*n)];
    dft16<SIGN>(x);
    A[swz(base)] = x[0];
    const float2 w1 = ldT<SIGN>(T, es);
    A[swz(base + stride)] = cmul(x[1], w1);
    const float2 w2 = cmul(w1, w1);
    A[swz(base + stride*2)] = cmul(x[2], w2);
    const float2 w3 = cmul(w1, w2);
    A[swz(base + stride*3)] = cmul(x[3], w3);
    const float2 w4 = cmul(w2, w2);
    A[swz(base + stride*4)] = cmul(x[4], w4);
    A[swz(base + stride*5)] = cmul(x[5], cmul(w1, w4));
    A[swz(base + stride*6)] = cmul(x[6], cmul(w2, w4));
    A[swz(base + stride*7)] = cmul(x[7], cmul(w3, w4));
    const float2 w8 = cmul(w4, w4);
    A[swz(base + stride*8)] = cmul(x[8], w8);
    A[swz(base + stride*9)]  = cmul(x[9],  cmul(w1, w8));
    A[swz(base + stride*10)] = cmul(x[10], cmul(w2, w8));
    A[swz(base + stride*11)] = cmul(x[11], cmul(w3, w8));
    const float2 w12 = cmul(w4, w8);
    A[swz(base + stride*12)] = cmul(x[12], w12);
    A[swz(base + stride*13)] = cmul(x[13], cmul(w1, w12));
    A[swz(base + stride*14)] = cmul(x[14], cmul(w2, w12));
    A[swz(base + stride*15)] = cmul(x[15], cmul(w3, w12));
}

// ---------------------------------------------------------------------------
// Kernel 1: forward real FFT (length 16384) via 8192-pt complex FFT.
// ---------------------------------------------------------------------------
__global__ __launch_bounds__(NT, 4)
void fwd_fft_kernel(const float* __restrict__ xi, const float* __restrict__ w,
                    const float* __restrict__ tmpl, const float2* __restrict__ T,
                    float2* __restrict__ spec) {
    __shared__ float2 A[M_LEN];   // 64 KB, swizzled
    const int sig = blockIdx.x;
    const int tid = threadIdx.x;

    const float* src;
    int nre;
    if (sig < 64)      { src = xi   + sig * L_LEN;         nre = L_LEN; }
    else if (sig < 66) { src = w    + (sig - 64) * L_LEN;  nre = L_LEN; }
    else               { src = tmpl + (sig - 66) * KT_LEN; nre = KT_LEN; }
    const int nc = nre >> 1;
    const float4* s4 = (const float4*)src;
    #pragma unroll
    for (int m = 0; m < 8; ++m) {
        const int u = 2*tid + 1024*m;
        float4 vv = (u < nc) ? s4[tid + 512*m] : make_float4(0.f, 0.f, 0.f, 0.f);
        ((float4*)A)[swz(u) >> 1] = vv;
    }
    __syncthreads();

    fft_stage16<-1>(A, T, tid, 512, 2*tid);
    __syncthreads();
    { const int blk = tid >> 5, j = tid & 31;
      fft_stage16<-1>(A, T, blk*512 + j, 32, 32*j); }
    __syncthreads();
    { const int blk = tid >> 1, j = tid & 1;
      fft_stage16<-1>(A, T, blk*32 + j, 2, 512*j); }
    __syncthreads();
    // Final radix-2 (stride 1, no twiddle), b128 in-place.
    #pragma unroll
    for (int m = 0; m < 8; ++m) {
        const int gi = swz(2*(tid + 512*m)) >> 1;
        float4 pq = ((float4*)A)[gi];
        ((float4*)A)[gi] = make_float4(pq.x + pq.z, pq.y + pq.w,
                                       pq.x - pq.z, pq.y - pq.w);
    }
    __syncthreads();

    // Untangle packed result to real-signal spectrum X[f], f = 0..M.
    float2* out = spec + (size_t)sig * SPEC_STRIDE;
    #pragma unroll
    for (int m = 0; m < 16; ++m) {
        const int f = tid + 512*m;
        const int fb = (M_LEN - f) & (M_LEN - 1);
        float2 Za = A[swz(pos(f))];
        float2 Zb = A[swz(pos(fb))];
        float2 E = make_float2(0.5f*(Za.x + Zb.x), 0.5f*(Za.y - Zb.y));
        float2 D = make_float2(Za.x - Zb.x, Za.y + Zb.y);
        float2 O = make_float2(0.5f*D.y, -0.5f*D.x);
        float2 t = T[f];
        float2 TO = make_float2(t.x*O.x - t.y*O.y, t.x*O.y + t.y*O.x);
        out[f] = make_float2(E.x + TO.x, E.y + TO.y);
    }
    if (tid == 0) {   // f = 8192: fa = fb = 0
        float2 Za = A[swz(0)];
        float2 E = make_float2(Za.x, 0.f);
        float2 O = make_float2(Za.y, 0.f);
        float2 t = T[M_LEN];                  // (-1, 0)
        float2 TO = make_float2(t.x*O.x, t.x*O.y);
        out[M_LEN] = make_float2(E.x + TO.x, E.y + TO.y);
    }
}

// ---------------------------------------------------------------------------
// Kernel 1.5: per (b,c) premultiply: D[f] = X[f]*conj(W[f])*e^{-i pi k/M}.
// ---------------------------------------------------------------------------
__global__ __launch_bounds__(512)
void premul_kernel(const float2* __restrict__ T, float2* __restrict__ spec) {
    const int bc = blockIdx.x;
    const int tid = threadIdx.x;
    const int c = bc & 1;
    float2* Xs = spec + (size_t)bc * SPEC_STRIDE;
    const float2* Ws = spec + (size_t)(64 + c) * SPEC_STRIDE;
    for (int f = tid; f <= M_LEN; f += 512) {
        float2 t = cmulc(Xs[f], Ws[f]);
        const int k = (4094 * f) & (L_LEN - 1);
        Xs[f] = cmul(t, T[k]);
    }
}

// ---------------------------------------------------------------------------
// Kernel 2: per (b,n,c): S[f] = D[f]*conj(H[f]); Hermitian pack fused into
// the product pass; 3 register radix-16 stages; final radix-2 fused with max.
// ---------------------------------------------------------------------------
__global__ __launch_bounds__(NT, 4)
void inv_fft_kernel(const float2* __restrict__ spec, const float2* __restrict__ T,
                    const float* __restrict__ hh, float* __restrict__ zarr) {
    __shared__ float2 A[M_LEN];   // 64 KB, swizzled (reused for reduction)
    const int idx = blockIdx.x;
    const int c = idx & 1;
    const int n = (idx >> 1) % NTPL;
    const int b = idx / (2 * NTPL);
    const int tid = threadIdx.x;

    const float2* Ds = spec + (size_t)(b*2 + c)      * SPEC_STRIDE;
    const float2* Hs = spec + (size_t)(66 + n*2 + c) * SPEC_STRIDE;
    const float4* D4 = (const float4*)Ds;
    const float4* H4 = (const float4*)Hs;
    const float4* T4 = (const float4*)T;

    // Fused product + Hermitian pack: thread t handles f = 2t+1024m+{0,1}
    // (f in [0,4096)) and partners 8192-f. Writes all of Z'[0..8191].
    #pragma unroll
    for (int m = 0; m < 4; ++m) {
        const int u = 2*tid + 1024*m;
        float4 df = D4[tid + 512*m], hf = H4[tid + 512*m];
        float2 Sa0 = cmulc(make_float2(df.x, df.y), make_float2(hf.x, hf.y));
        float2 Sa1 = cmulc(make_float2(df.z, df.w), make_float2(hf.z, hf.w));
        float2 Sb0 = cmulc(Ds[M_LEN - u],     Hs[M_LEN - u]);
        float2 Sb1 = cmulc(Ds[M_LEN - 1 - u], Hs[M_LEN - 1 - u]);
        float4 tw = T4[tid + 512*m];          // T[u], T[u+1]
        // f = u
        float cs0 = tw.x, sn0 = -tw.y;
        float Ex0 = 0.5f*(Sa0.x + Sb0.x), Ey0 = 0.5f*(Sa0.y - Sb0.y);
        float Dx0 = Sa0.x - Sb0.x,        Dy0 = Sa0.y + Sb0.y;
        float Ox0 = 0.5f*(cs0*Dx0 - sn0*Dy0), Oy0 = 0.5f*(cs0*Dy0 + sn0*Dx0);
        // f = u+1
        float cs1 = tw.z, sn1 = -tw.w;
        float Ex1 = 0.5f*(Sa1.x + Sb1.x), Ey1 = 0.5f*(Sa1.y - Sb1.y);
        float Dx1 = Sa1.x - Sb1.x,        Dy1 = Sa1.y + Sb1.y;
        float Ox1 = 0.5f*(cs1*Dx1 - sn1*Dy1), Oy1 = 0.5f*(cs1*Dy1 + sn1*Dx1);
        ((float4*)A)[swz(u) >> 1] = make_float4(Ex0 - Oy0, Ey0 + Ox0,
                                                Ex1 - Oy1, Ey1 + Ox1);
        if (u > 0) A[swz(M_LEN - u)] = make_float2(Ex0 + Oy0, Ox0 - Ey0);
        A[swz(M_LEN - 1 - u)] = make_float2(Ex1 + Oy1, Ox1 - Ey1);
    }
    if (tid == 0) {   // f = 4096 (self-paired)
        float2 S = cmulc(Ds[4096], Hs[4096]);
        A[swz(4096)] = make_float2(S.x, -S.y);
    }
    __syncthreads();

    fft_stage16<+1>(A, T, tid, 512, 2*tid);
    __syncthreads();
    { const int blk = tid >> 5, j = tid & 31;
      fft_stage16<+1>(A, T, blk*512 + j, 32, 32*j); }
    __syncthreads();
    { const int blk = tid >> 1, j = tid & 1;
      fft_stage16<+1>(A, T, blk*32 + j, 2, 512*j); }
    __syncthreads();

    // Final radix-2 fused with max over re/im of every time sample.
    float mx = -INFINITY;
    #pragma unroll
    for (int m = 0; m < 8; ++m) {
        float4 pq = ((const float4*)A)[swz(2*(tid + 512*m)) >> 1];
        mx = fmaxf(mx, fmaxf(fmaxf(pq.x + pq.z, pq.y + pq.w),
                             fmaxf(pq.x - pq.z, pq.y - pq.w)));
    }
    __syncthreads();   // all reads of A done before reusing it as scratch
    for (int off = 32; off > 0; off >>= 1)
        mx = fmaxf(mx, __shfl_xor(mx, off));
    const int lane = tid & 63, wv = tid >> 6;   // 8 waves
    float* redf = (float*)A;
    if (lane == 0) redf[wv] = mx;
    __syncthreads();
    if (tid == 0) {
        float mm = redf[0];
        for (int i = 1; i < NT/64; ++i) mm = fmaxf(mm, redf[i]);
        zarr[(b*2 + c)*NTPL + n] = mm / ((float)M_LEN * hh[n*2 + c]);
    }
}

// ---------------------------------------------------------------------------
// Kernel 3: tiny CNN/MLP head. One block per batch element.
// ---------------------------------------------------------------------------
__global__ __launch_bounds__(256)
void head_kernel(const float* __restrict__ zarr,
                 const float* __restrict__ W1, const float* __restrict__ b1,
                 const float* __restrict__ W2, const float* __restrict__ b2,
                 const float* __restrict__ W3, const float* __restrict__ b3,
                 const float* __restrict__ W4, const float* __restrict__ b4,
                 float* __restrict__ out) {
    __shared__ float zl[2][NTPL];
    __shared__ float s1[16][48];
    __shared__ float p1[16][16];
    __shared__ float s2[32][14];
    __shared__ float hflat[128];
    __shared__ float h1[32];
    const int b = blockIdx.x, tid = threadIdx.x;

    for (int i = tid; i < 2*NTPL; i += 256) zl[i/NTPL][i%NTPL] = zarr[b*2*NTPL + i];
    __syncthreads();
    for (int i = tid; i < 16*48; i += 256) {
        const int o = i / 48, t = i % 48;
        float acc = b1[o];
        #pragma unroll
        for (int cc = 0; cc < 2; ++cc)
            #pragma unroll
            for (int k = 0; k < 3; ++k)
                acc += zl[cc][t+k] * W1[o*6 + cc*3 + k];
        s1[o][t] = 1.f / (1.f + __expf(-acc));
    }
    __syncthreads();
    for (int i = tid; i < 16*16; i += 256) {
        const int o = i / 16, u = i % 16;
        p1[o][u] = fmaxf(fmaxf(s1[o][3*u], s1[o][3*u+1]), s1[o][3*u+2]);
    }
    __syncthreads();
    for (int i = tid; i < 32*14; i += 256) {
        const int o = i / 14, t = i % 14;
        float acc = b2[o];
        for (int cc = 0; cc < 16; ++cc)
            #pragma unroll
            for (int k = 0; k < 3; ++k)
                acc += p1[cc][t+k] * W2[o*48 + cc*3 + k];
        s2[o][t] = 1.f / (1.f + __expf(-acc));
    }
    __syncthreads();
    for (int i = tid; i < 128; i += 256) {
        const int o = i / 4, u = i % 4;
        hflat[i] = fmaxf(fmaxf(s2[o][3*u], s2[o][3*u+1]), s2[o][3*u+2]);
    }
    __syncthreads();
    if (tid < 32) {
        float acc = b3[tid];
        for (int j = 0; j < 128; ++j) acc += hflat[j] * W3[tid*128 + j];
        h1[tid] = fmaxf(acc, 0.f);
    }
    __syncthreads();
    if (tid < 2) {
        float acc = b4[tid];
        for (int j = 0; j < 32; ++j) acc += h1[j] * W4[tid*32 + j];
        out[b*2 + tid] = acc;
    }
}

extern "C" void kernel_launch(void* const* d_in, const int* in_sizes, int n_in,
                              void* d_out, int out_size, void* d_ws, size_t ws_size,
                              hipStream_t stream) {
    const float* xi   = (const float*)d_in[0];
    const float* Sw   = (const float*)d_in[1];
    const float* tmpl = (const float*)d_in[2];
    const float* hh   = (const float*)d_in[3];
    const float* W1   = (const float*)d_in[4];
    const float* b1   = (const float*)d_in[5];
    const float* W2   = (const float*)d_in[6];
    const float* b2   = (const float*)d_in[7];
    const float* W3   = (const float*)d_in[8];
    const float* b3   = (const float*)d_in[9];
    const float* W4   = (const float*)d_in[10];
    const float* b4   = (const float*)d_in[11];
    float* out = (float*)d_out;

    float2* T16  = (float2*)d_ws;                       // 16384 float2 = 128 KB
    float2* spec = T16 + 16384;                         // NSIG * SPEC_STRIDE float2
    float*  zarr = (float*)(spec + (size_t)NSIG * SPEC_STRIDE);

    twiddle_init<<<dim3(32), dim3(512), 0, stream>>>(T16);
    fwd_fft_kernel<<<dim3(NSIG), dim3(NT), 0, stream>>>(xi, Sw, tmpl, T16, spec);
    premul_kernel<<<dim3(64), dim3(512), 0, stream>>>(T16, spec);
    inv_fft_kernel<<<dim3(BB * NTPL * 2), dim3(NT), 0, stream>>>(spec, T16, hh, zarr);
    head_kernel<<<dim3(BB), dim3(256), 0, stream>>>(zarr, W1, b1, W2, b2, W3, b3, W4, b4, out);
}

// Round 6
// 162.848 us; speedup vs baseline: 1.6154x; 1.1303x over previous
//
#include <hip/hip_runtime.h>
#include <math.h>

#define L_LEN 16384
#define M_LEN 8192
#define KT_LEN 4096
#define BB 32
#define NTPL 50
#define SPEC_STRIDE 8224   // complex slots per signal (>= 8193)
#define NSIG 166           // 64 x-signals + 2 w-signals + 100 templates
#define NT 512
#define PI_F 3.14159265358979323846f

typedef float cf2 __attribute__((ext_vector_type(2)));

// Complex helpers on a 2-wide float vector: written so the backend can select
// packed v_pk_{add,mul,fma}_f32 (R5 showed half the VALU stream is unpacked
// scalar float ops + moves).
__device__ __forceinline__ cf2 cmul(cf2 a, cf2 b) {
    cf2 byx = __builtin_shufflevector(b, b, 1, 0);   // (by,bx)
    return (cf2){a.x, a.x} * b + (cf2){-a.y, a.y} * byx;
}
__device__ __forceinline__ cf2 cmulc(cf2 a, cf2 b) { // a * conj(b)
    return a * (cf2){b.x, b.x} + (cf2){a.y, -a.x} * (cf2){b.y, b.y};
}
// SIGN=-1: *(-i) ; SIGN=+1: *(+i)
template<int SIGN>
__device__ __forceinline__ cf2 rot90(cf2 z) {
    return (SIGN < 0) ? (cf2){z.y, -z.x} : (cf2){-z.y, z.x};
}
template<int SIGN>
__device__ __forceinline__ cf2 ldT(const cf2* __restrict__ T, int idx) {
    cf2 t = T[idx];
    if (SIGN > 0) t.y = -t.y;
    return t;
}

// Generic LDS bank swizzle (used only on cold paths; hot paths use the
// per-stage algebraic reductions below). Even XOR keeps float4 pairs intact.
__device__ __forceinline__ int swz(int i) { return i ^ (((i >> 5) & 15) << 1); }

// Position of frequency f after radix 16,16,16,2 DIF stages (digit reversal).
__device__ __forceinline__ int pos(int f) {
    return ((f & 15) << 9) | (((f >> 4) & 15) << 5) |
           (((f >> 8) & 15) << 1) | ((f >> 12) & 1);
}

// 16-point DFT in registers, natural order. Inner twiddles are constants.
template<int SIGN>
__device__ __forceinline__ void dft16(cf2 x[16]) {
    const float S = (SIGN < 0) ? -1.f : 1.f;
    const cf2 w1 = {0.9238795325112867f, S * 0.3826834323650898f};
    const cf2 w2 = {0.7071067811865476f, S * 0.7071067811865476f};
    const cf2 w3 = {0.3826834323650898f, S * 0.9238795325112867f};
    cf2 v[16];
    #pragma unroll
    for (int n1 = 0; n1 < 4; ++n1) {
        cf2 a0 = x[n1], a1 = x[n1+4], a2 = x[n1+8], a3 = x[n1+12];
        cf2 t0 = a0 + a2, t2 = a0 - a2;
        cf2 t1 = a1 + a3, t3 = rot90<SIGN>(a1 - a3);
        cf2 u0 = t0 + t1, u1 = t2 + t3;
        cf2 u2 = t0 - t1, u3 = t2 - t3;
        if (n1 == 1) { u1 = cmul(u1, w1); u2 = cmul(u2, w2); u3 = cmul(u3, w3); }
        else if (n1 == 2) { u1 = cmul(u1, w2); u2 = rot90<SIGN>(u2);
                            u3 = rot90<SIGN>(cmul(u3, w2)); }
        else if (n1 == 3) { u1 = cmul(u1, w3); u2 = rot90<SIGN>(cmul(u2, w2));
                            u3 = -cmul(u3, w1); }
        v[0*4+n1] = u0; v[1*4+n1] = u1; v[2*4+n1] = u2; v[3*4+n1] = u3;
    }
    #pragma unroll
    for (int r = 0; r < 4; ++r) {
        cf2 a0 = v[r*4+0], a1 = v[r*4+1], a2 = v[r*4+2], a3 = v[r*4+3];
        cf2 t0 = a0 + a2, t2 = a0 - a2;
        cf2 t1 = a1 + a3, t3 = rot90<SIGN>(a1 - a3);
        x[r]    = t0 + t1; x[r+4]  = t2 + t3;
        x[r+8]  = t0 - t1; x[r+12] = t2 - t3;
    }
}

// Radix-16 butterfly at 16 precomputed LDS indices; outer twiddles from a
// single w1 via power chain (R5: scattered table loads were the stall).
template<int SIGN>
__device__ __forceinline__ void butterfly16(cf2* A, const int idx[16], cf2 w1) {
    cf2 x[16];
    #pragma unroll
    for (int n = 0; n < 16; ++n) x[n] = A[idx[n]];
    dft16<SIGN>(x);
    A[idx[0]] = x[0];
    A[idx[1]] = cmul(x[1], w1);
    const cf2 w2 = cmul(w1, w1);
    A[idx[2]] = cmul(x[2], w2);
    const cf2 w3 = cmul(w1, w2);
    A[idx[3]] = cmul(x[3], w3);
    const cf2 w4 = cmul(w2, w2);
    A[idx[4]] = cmul(x[4], w4);
    A[idx[5]] = cmul(x[5], cmul(w1, w4));
    A[idx[6]] = cmul(x[6], cmul(w2, w4));
    A[idx[7]] = cmul(x[7], cmul(w3, w4));
    const cf2 w8 = cmul(w4, w4);
    A[idx[8]]  = cmul(x[8],  w8);
    A[idx[9]]  = cmul(x[9],  cmul(w1, w8));
    A[idx[10]] = cmul(x[10], cmul(w2, w8));
    A[idx[11]] = cmul(x[11], cmul(w3, w8));
    const cf2 w12 = cmul(w4, w8);
    A[idx[12]] = cmul(x[12], w12);
    A[idx[13]] = cmul(x[13], cmul(w1, w12));
    A[idx[14]] = cmul(x[14], cmul(w2, w12));
    A[idx[15]] = cmul(x[15], cmul(w3, w12));
}

// Per-stage swizzled index sets, algebraically reduced (verified):
// stage1: swz(tid+512n)        = swz(tid) + 512n
// stage2: swz(blk*512+j+32n)   = blk*512 + 32n + (j^2n)        (j in [0,32))
// stage3: swz(blk*32+j+2n)     = blk*32 + j + ((2n)^((blk&15)<<1))
template<int SIGN, bool TBL>
__device__ __forceinline__ void fft_3stages(cf2* A, const cf2* __restrict__ T, int tid) {
    {   // stage 1: stride 512, es = 2*tid
        int idx[16]; const int b0 = swz(tid);
        #pragma unroll
        for (int n = 0; n < 16; ++n) idx[n] = b0 + 512*n;
        cf2 w1;
        if (TBL) w1 = ldT<SIGN>(T, 2*tid);
        else { float sn, cs; __sincosf((float)SIGN * PI_F * (float)(2*tid) / 8192.f, &sn, &cs);
               w1 = (cf2){cs, sn}; }
        butterfly16<SIGN>(A, idx, w1);
    }
    __syncthreads();
    {   // stage 2: stride 32, es = 32*j
        const int blk = tid >> 5, j = tid & 31, jb = blk*512;
        int idx[16];
        #pragma unroll
        for (int n = 0; n < 16; ++n) idx[n] = jb + 32*n + (j ^ (2*n));
        cf2 w1;
        if (TBL) w1 = ldT<SIGN>(T, 32*j);
        else { float sn, cs; __sincosf((float)SIGN * PI_F * (float)(32*j) / 8192.f, &sn, &cs);
               w1 = (cf2){cs, sn}; }
        butterfly16<SIGN>(A, idx, w1);
    }
    __syncthreads();
    {   // stage 3: stride 2, es = 512*j
        const int blk = tid >> 1, j = tid & 1;
        const int xv = (blk & 15) << 1, b3 = blk*32 + j;
        int idx[16];
        #pragma unroll
        for (int n = 0; n < 16; ++n) idx[n] = b3 + ((2*n) ^ xv);
        cf2 w1;
        if (TBL) w1 = ldT<SIGN>(T, 512*j);
        else { float sn, cs; __sincosf((float)SIGN * PI_F * (float)(512*j) / 8192.f, &sn, &cs);
               w1 = (cf2){cs, sn}; }
        butterfly16<SIGN>(A, idx, w1);
    }
    __syncthreads();
}

// ---------------------------------------------------------------------------
// Kernel 1: forward real FFT (length 16384) via 8192-pt complex FFT.
// Blocks [NSIG, NSIG+32) instead build the twiddle table T (used by later
// kernels only — fwd itself uses inline __sincosf, so no dependency).
// ---------------------------------------------------------------------------
__global__ __launch_bounds__(NT, 4)
void fwd_fft_kernel(const float* __restrict__ xi, const float* __restrict__ w,
                    const float* __restrict__ tmpl, cf2* __restrict__ Tw,
                    cf2* __restrict__ spec) {
    __shared__ __attribute__((aligned(16))) cf2 A[M_LEN];   // 64 KB
    const int sig = blockIdx.x;
    const int tid = threadIdx.x;

    if (sig >= NSIG) {   // twiddle writer: T[k] = e^{-2 pi i k / 16384}
        const int k = (sig - NSIG) * NT + tid;
        const double a = -M_PI * (double)k / 8192.0;
        Tw[k] = (cf2){(float)cos(a), (float)sin(a)};
        return;
    }

    const float* src;
    int nre;
    if (sig < 64)      { src = xi   + sig * L_LEN;         nre = L_LEN; }
    else if (sig < 66) { src = w    + (sig - 64) * L_LEN;  nre = L_LEN; }
    else               { src = tmpl + (sig - 66) * KT_LEN; nre = KT_LEN; }
    const int nc = nre >> 1;
    const float4* s4 = (const float4*)src;
    const int g0 = tid ^ ((tid >> 4) & 15);   // = swz(2*tid+1024m)>>1 − 512m
    #pragma unroll
    for (int m = 0; m < 8; ++m) {
        const int u = 2*tid + 1024*m;
        float4 vv = (u < nc) ? s4[tid + 512*m] : make_float4(0.f, 0.f, 0.f, 0.f);
        ((float4*)A)[g0 + 512*m] = vv;
    }
    __syncthreads();

    fft_3stages<-1, false>(A, nullptr, tid);

    // Final radix-2 (stride 1, no twiddle), b128 in-place.
    #pragma unroll
    for (int m = 0; m < 8; ++m) {
        float4 pq = ((float4*)A)[g0 + 512*m];
        ((float4*)A)[g0 + 512*m] = make_float4(pq.x + pq.z, pq.y + pq.w,
                                               pq.x - pq.z, pq.y - pq.w);
    }
    __syncthreads();

    // Untangle packed result to real-signal spectrum X[f], f = 0..M.
    cf2* out = spec + (size_t)sig * SPEC_STRIDE;
    #pragma unroll
    for (int m = 0; m < 16; ++m) {
        const int f = tid + 512*m;
        const int fb = (M_LEN - f) & (M_LEN - 1);
        cf2 Za = A[swz(pos(f))];
        cf2 Zb = A[swz(pos(fb))];
        cf2 E = (cf2){0.5f*(Za.x + Zb.x), 0.5f*(Za.y - Zb.y)};
        cf2 D = (cf2){Za.x - Zb.x, Za.y + Zb.y};
        cf2 O = (cf2){0.5f*D.y, -0.5f*D.x};
        float sn, cs;
        __sincosf(-PI_F * (float)f / 8192.f, &sn, &cs);
        cf2 TO = (cf2){cs*O.x - sn*O.y, cs*O.y + sn*O.x};
        out[f] = E + TO;
    }
    if (tid == 0) {   // f = 8192
        cf2 Za = A[swz(0)];
        out[M_LEN] = (cf2){Za.x - Za.y, 0.f};
    }
}

// ---------------------------------------------------------------------------
// Kernel 1.5: per (b,c) premultiply: D[f] = X[f]*conj(W[f])*phase(f), with
// phase(f) = e^{-2 pi i 4094 f/16384} = conj(T[2f mod 16K]) * (-i)^f
// (coalesced T loads instead of the old full-table scatter).
// ---------------------------------------------------------------------------
__global__ __launch_bounds__(512)
void premul_kernel(const cf2* __restrict__ T, cf2* __restrict__ spec) {
    const int bc = blockIdx.x;
    const int tid = threadIdx.x;
    const int c = bc & 1;
    cf2* Xs = spec + (size_t)bc * SPEC_STRIDE;
    const cf2* Ws = spec + (size_t)(64 + c) * SPEC_STRIDE;
    const int r = tid & 3;   // f == tid (mod 4) for every iteration
    for (int f = tid; f <= M_LEN; f += 512) {
        cf2 t = cmulc(Xs[f], Ws[f]);
        cf2 p = T[(2*f) & (L_LEN - 1)];
        cf2 s = cmulc(t, p);
        cf2 o;
        if (r == 0)      o = s;
        else if (r == 1) o = (cf2){s.y, -s.x};    // * -i
        else if (r == 2) o = -s;
        else             o = (cf2){-s.y, s.x};    // * +i
        Xs[f] = o;
    }
}

// ---------------------------------------------------------------------------
// Kernel 2: per (b,n,c): S[f] = D[f]*conj(H[f]); Hermitian pack fused into
// the product pass; 3 register radix-16 stages; final radix-2 fused with max.
// ---------------------------------------------------------------------------
__global__ __launch_bounds__(NT, 4)
void inv_fft_kernel(const cf2* __restrict__ spec, const cf2* __restrict__ T,
                    const float* __restrict__ hh, float* __restrict__ zarr) {
    __shared__ __attribute__((aligned(16))) cf2 A[M_LEN];   // 64 KB
    const int idx = blockIdx.x;
    const int c = idx & 1;
    const int n = (idx >> 1) % NTPL;
    const int b = idx / (2 * NTPL);
    const int tid = threadIdx.x;

    const cf2* Ds = spec + (size_t)(b*2 + c)      * SPEC_STRIDE;
    const cf2* Hs = spec + (size_t)(66 + n*2 + c) * SPEC_STRIDE;
    const float4* D4 = (const float4*)Ds;
    const float4* H4 = (const float4*)Hs;
    const float4* T4 = (const float4*)T;
    const int g0 = tid ^ ((tid >> 4) & 15);

    // Fused product + Hermitian pack: thread t handles f = 2t+1024m+{0,1}
    // (f in [0,4096)) and partners 8192-f. Writes all of Z'[0..8191].
    #pragma unroll
    for (int m = 0; m < 4; ++m) {
        const int u = 2*tid + 1024*m;
        float4 df = D4[tid + 512*m], hf = H4[tid + 512*m];
        cf2 Sa0 = cmulc((cf2){df.x, df.y}, (cf2){hf.x, hf.y});
        cf2 Sa1 = cmulc((cf2){df.z, df.w}, (cf2){hf.z, hf.w});
        cf2 Sb0 = cmulc(Ds[M_LEN - u],     Hs[M_LEN - u]);
        cf2 Sb1 = cmulc(Ds[M_LEN - 1 - u], Hs[M_LEN - 1 - u]);
        float4 tw = T4[tid + 512*m];          // T[u], T[u+1]
        // f = u
        float cs0 = tw.x, sn0 = -tw.y;
        float Ex0 = 0.5f*(Sa0.x + Sb0.x), Ey0 = 0.5f*(Sa0.y - Sb0.y);
        float Dx0 = Sa0.x - Sb0.x,        Dy0 = Sa0.y + Sb0.y;
        float Ox0 = 0.5f*(cs0*Dx0 - sn0*Dy0), Oy0 = 0.5f*(cs0*Dy0 + sn0*Dx0);
        // f = u+1
        float cs1 = tw.z, sn1 = -tw.w;
        float Ex1 = 0.5f*(Sa1.x + Sb1.x), Ey1 = 0.5f*(Sa1.y - Sb1.y);
        float Dx1 = Sa1.x - Sb1.x,        Dy1 = Sa1.y + Sb1.y;
        float Ox1 = 0.5f*(cs1*Dx1 - sn1*Dy1), Oy1 = 0.5f*(cs1*Dy1 + sn1*Dx1);
        ((float4*)A)[g0 + 512*m] = make_float4(Ex0 - Oy0, Ey0 + Ox0,
                                               Ex1 - Oy1, Ey1 + Ox1);
        if (u > 0) A[swz(M_LEN - u)] = (cf2){Ex0 + Oy0, Ox0 - Ey0};
        A[swz(M_LEN - 1 - u)] = (cf2){Ex1 + Oy1, Ox1 - Ey1};
    }
    if (tid == 0) {   // f = 4096 (self-paired)
        cf2 S = cmulc(Ds[4096], Hs[4096]);
        A[swz(4096)] = (cf2){S.x, -S.y};
    }
    __syncthreads();

    fft_3stages<+1, true>(A, T, tid);

    // Final radix-2 fused with max over re/im of every time sample.
    float mx = -INFINITY;
    #pragma unroll
    for (int m = 0; m < 8; ++m) {
        float4 pq = ((const float4*)A)[g0 + 512*m];
        mx = fmaxf(mx, fmaxf(fmaxf(pq.x + pq.z, pq.y + pq.w),
                             fmaxf(pq.x - pq.z, pq.y - pq.w)));
    }
    __syncthreads();   // all reads of A done before reusing it as scratch
    for (int off = 32; off > 0; off >>= 1)
        mx = fmaxf(mx, __shfl_xor(mx, off));
    const int lane = tid & 63, wv = tid >> 6;   // 8 waves
    float* redf = (float*)A;
    if (lane == 0) redf[wv] = mx;
    __syncthreads();
    if (tid == 0) {
        float mm = redf[0];
        for (int i = 1; i < NT/64; ++i) mm = fmaxf(mm, redf[i]);
        zarr[(b*2 + c)*NTPL + n] = mm / ((float)M_LEN * hh[n*2 + c]);
    }
}

// ---------------------------------------------------------------------------
// Kernel 3: tiny CNN/MLP head. One block per batch element.
// ---------------------------------------------------------------------------
__global__ __launch_bounds__(256)
void head_kernel(const float* __restrict__ zarr,
                 const float* __restrict__ W1, const float* __restrict__ b1,
                 const float* __restrict__ W2, const float* __restrict__ b2,
                 const float* __restrict__ W3, const float* __restrict__ b3,
                 const float* __restrict__ W4, const float* __restrict__ b4,
                 float* __restrict__ out) {
    __shared__ float zl[2][NTPL];
    __shared__ float s1[16][48];
    __shared__ float p1[16][16];
    __shared__ float s2[32][14];
    __shared__ float hflat[128];
    __shared__ float h1[32];
    const int b = blockIdx.x, tid = threadIdx.x;

    for (int i = tid; i < 2*NTPL; i += 256) zl[i/NTPL][i%NTPL] = zarr[b*2*NTPL + i];
    __syncthreads();
    for (int i = tid; i < 16*48; i += 256) {
        const int o = i / 48, t = i % 48;
        float acc = b1[o];
        #pragma unroll
        for (int cc = 0; cc < 2; ++cc)
            #pragma unroll
            for (int k = 0; k < 3; ++k)
                acc += zl[cc][t+k] * W1[o*6 + cc*3 + k];
        s1[o][t] = 1.f / (1.f + __expf(-acc));
    }
    __syncthreads();
    for (int i = tid; i < 16*16; i += 256) {
        const int o = i / 16, u = i % 16;
        p1[o][u] = fmaxf(fmaxf(s1[o][3*u], s1[o][3*u+1]), s1[o][3*u+2]);
    }
    __syncthreads();
    for (int i = tid; i < 32*14; i += 256) {
        const int o = i / 14, t = i % 14;
        float acc = b2[o];
        for (int cc = 0; cc < 16; ++cc)
            #pragma unroll
            for (int k = 0; k < 3; ++k)
                acc += p1[cc][t+k] * W2[o*48 + cc*3 + k];
        s2[o][t] = 1.f / (1.f + __expf(-acc));
    }
    __syncthreads();
    for (int i = tid; i < 128; i += 256) {
        const int o = i / 4, u = i % 4;
        hflat[i] = fmaxf(fmaxf(s2[o][3*u], s2[o][3*u+1]), s2[o][3*u+2]);
    }
    __syncthreads();
    if (tid < 32) {
        float acc = b3[tid];
        for (int j = 0; j < 128; ++j) acc += hflat[j] * W3[tid*128 + j];
        h1[tid] = fmaxf(acc, 0.f);
    }
    __syncthreads();
    if (tid < 2) {
        float acc = b4[tid];
        for (int j = 0; j < 32; ++j) acc += h1[j] * W4[tid*32 + j];
        out[b*2 + tid] = acc;
    }
}

extern "C" void kernel_launch(void* const* d_in, const int* in_sizes, int n_in,
                              void* d_out, int out_size, void* d_ws, size_t ws_size,
                              hipStream_t stream) {
    const float* xi   = (const float*)d_in[0];
    const float* Sw   = (const float*)d_in[1];
    const float* tmpl = (const float*)d_in[2];
    const float* hh   = (const float*)d_in[3];
    const float* W1   = (const float*)d_in[4];
    const float* b1   = (const float*)d_in[5];
    const float* W2   = (const float*)d_in[6];
    const float* b2   = (const float*)d_in[7];
    const float* W3   = (const float*)d_in[8];
    const float* b3   = (const float*)d_in[9];
    const float* W4   = (const float*)d_in[10];
    const float* b4   = (const float*)d_in[11];
    float* out = (float*)d_out;

    cf2* T16  = (cf2*)d_ws;                         // 16384 cf2 = 128 KB
    cf2* spec = T16 + 16384;                        // NSIG * SPEC_STRIDE cf2
    float* zarr = (float*)(spec + (size_t)NSIG * SPEC_STRIDE);

    // fwd grid: NSIG FFT blocks + 32 twiddle-table writer blocks (fused
    // twiddle_init; fwd itself uses inline __sincosf, no T dependency).
    fwd_fft_kernel<<<dim3(NSIG + 32), dim3(NT), 0, stream>>>(xi, Sw, tmpl, T16, spec);
    premul_kernel<<<dim3(64), dim3(512), 0, stream>>>(T16, spec);
    inv_fft_kernel<<<dim3(BB * NTPL * 2), dim3(NT), 0, stream>>>(spec, T16, hh, zarr);
    head_kernel<<<dim3(BB), dim3(256), 0, stream>>>(zarr, W1, b1, W2, b2, W3, b3, W4, b4, out);
}